// Round 9
// baseline (654.719 us; speedup 1.0000x reference)
//
#include <hip/hip_runtime.h>
#include <hip/hip_bf16.h>
#include <math.h>

#define LAYERS 4
#define IDIM 256
#define HDIM 512
#define NH 8
#define HD 64
#define FF 1024
#define SEQ 1024
#define BATCH 8
#define EPS 1e-5f

typedef __attribute__((ext_vector_type(8))) short short8;
typedef __attribute__((ext_vector_type(4))) short short4v;
typedef __attribute__((ext_vector_type(4))) float f32x4;
typedef __attribute__((ext_vector_type(4))) int int4v;
typedef __attribute__((ext_vector_type(2))) unsigned int uint2v;
typedef unsigned long long u64;

// fp32 -> bf16 (RNE) on raw bits
__device__ __forceinline__ short f2bf(float f) {
    unsigned u = __float_as_uint(f);
    u = (u + 0x7FFFu + ((u >> 16) & 1u)) >> 16;
    return (short)u;
}
__device__ __forceinline__ float bf2f(short s) {
    return __uint_as_float(((unsigned)(unsigned short)s) << 16);
}
__device__ __forceinline__ void gll16(const void* g, void* l) {
    __builtin_amdgcn_global_load_lds(
        (const __attribute__((address_space(1))) unsigned int*)g,
        (__attribute__((address_space(3))) unsigned int*)l, 16, 0, 0);
}

// ---------------------------------------------------------------------------
// merged fp32->bf16 conversion of all 5 weight tensors, 4 elems/thread.
#define CVT_P0 131072u
#define CVT_P1 3276800u
#define CVT_P2 4325376u
#define CVT_P3 6422528u
#define CVT_TOT 8519680u
__global__ __launch_bounds__(256) void cvt_all(const float* __restrict__ s0, short* __restrict__ d0,
                                               const float* __restrict__ s1, short* __restrict__ d1,
                                               const float* __restrict__ s2, short* __restrict__ d2,
                                               const float* __restrict__ s3, short* __restrict__ d3,
                                               const float* __restrict__ s4, short* __restrict__ d4) {
    size_t i = ((size_t)blockIdx.x * 256 + threadIdx.x) * 4;
    const float* s; short* d; size_t off;
    if (i < CVT_P0)      { s = s0; d = d0; off = i; }
    else if (i < CVT_P1) { s = s1; d = d1; off = i - CVT_P0; }
    else if (i < CVT_P2) { s = s2; d = d2; off = i - CVT_P1; }
    else if (i < CVT_P3) { s = s3; d = d3; off = i - CVT_P2; }
    else                 { s = s4; d = d4; off = i - CVT_P3; }
    f32x4 f = *(const f32x4*)(s + off);
    short4v o = {f2bf(f[0]), f2bf(f[1]), f2bf(f[2]), f2bf(f[3])};
    *(short4v*)(d + off) = o;
}

// nodes (S,B,I) fp32 -> xt (B*S, I) bf16, 4 elems/thread
__global__ __launch_bounds__(256) void transpose_nodes(const float* __restrict__ nodes,
                                                       short* __restrict__ xt) {
    size_t idx = ((size_t)blockIdx.x * 256 + threadIdx.x) * 4;
    int i  = idx & (IDIM - 1);
    int sb = idx >> 8;
    int b  = sb & (BATCH - 1);
    int s  = sb >> 3;
    f32x4 f = *(const f32x4*)(nodes + idx);
    short4v o = {f2bf(f[0]), f2bf(f[1]), f2bf(f[2]), f2bf(f[3])};
    *(short4v*)(xt + ((size_t)b * SEQ + s) * IDIM + i) = o;
}

// ---------------------------------------------------------------------------
__global__ __launch_bounds__(256) void build_masks(const int* __restrict__ dist,
                                                   u64* __restrict__ mS,
                                                   u64* __restrict__ mL,
                                                   u64* __restrict__ mG) {
    int t = blockIdx.x * 256 + threadIdx.x;      // B*S*16 = 131072
    int w = t & 15, q = (t >> 4) & 1023, b = t >> 14;
    const int4v* dp = (const int4v*)(dist + ((size_t)b * SEQ + q) * SEQ + w * 64);
    u64 bs = 0, bl = 0;
#pragma unroll
    for (int i = 0; i < 16; i++) {
        int4v d = dp[i];
#pragma unroll
        for (int j = 0; j < 4; j++) {
            bs |= (u64)(d[j] == 1) << (i * 4 + j);
            bl |= (u64)(d[j] >= 1) << (i * 4 + j);
        }
    }
    mS[((size_t)b * SEQ + q) * 16 + w] = bs;
    mL[((size_t)b * SEQ + q) * 16 + w] = bl;
    if (q == 0) mG[b * 16 + w] = bl;
}

// ---------------------------------------------------------------------------
// bf16 MFMA GEMM (16x16x32), DOUBLE-BUFFERED single-barrier K-loop:
// per iter: barrier (drains this iter's async loads) -> issue next-tile
// global_load_lds into the other buffer -> compute current. Critical path
// per iter becomes max(load, compute) instead of load+compute, and barriers
// halve. BM=64, BK=64: LDS 2x24KB = 48KB -> 3 blocks/CU.
// If vt != null, column blocks with n0 >= 1024 (V-projection) are written
// transposed into Vt (B,NH,HD,S) paired-chunk layout instead of C.
template<int BM, int BK>
__global__ __launch_bounds__(256, 3)
void gemm_bf16(const short* __restrict__ A, const short* __restrict__ W,
               const float* __restrict__ bias, short* __restrict__ C,
               short* __restrict__ vt, int M, int N, int K, int relu) {
    constexpr int UPR = BK / 8;          // 16B units per row
    constexpr int RPC = 1024 / (BK * 2); // rows per 1KB staging chunk
    constexpr int ACH = BM * BK * 2 / 1024;   // A staging chunks
    constexpr int WCH = 128 * BK * 2 / 1024;  // W staging chunks
    __shared__ __align__(16) short As[2][BM * BK];
    __shared__ __align__(16) short Ws[2][128 * BK];
    const int tid = threadIdx.x;
    const int w = tid >> 6, lane = tid & 63;
    const int l15 = lane & 15, quad = lane >> 4;
    const int m0 = blockIdx.y * BM, n0 = blockIdx.x * 128;

    constexpr int NI = (BM == 128) ? 4 : 2;
    const int wm = (BM == 128) ? (w >> 1) * 64 : 0;
    const int wn = (BM == 128) ? (w & 1) * 64 : w * 32;

    f32x4 acc[4][NI];
#pragma unroll
    for (int mi = 0; mi < 4; mi++)
#pragma unroll
        for (int ni = 0; ni < NI; ni++) acc[mi][ni] = (f32x4){0.f, 0.f, 0.f, 0.f};

    const int r_in = lane / UPR;
    const int c8   = lane % UPR;

    auto stage = [&](int buf, int k0) {
#pragma unroll
        for (int rep = 0; rep < ACH / 4; rep++) {
            int chunk = rep * 4 + w;
            int row = chunk * RPC + r_in;
            gll16(A + (size_t)(m0 + row) * K + k0 + ((c8 ^ (row & (UPR - 1))) << 3),
                  (char*)As[buf] + chunk * 1024);
        }
#pragma unroll
        for (int rep = 0; rep < WCH / 4; rep++) {
            int chunk = rep * 4 + w;
            int row = chunk * RPC + r_in;
            gll16(W + (size_t)(n0 + row) * K + k0 + ((c8 ^ (row & (UPR - 1))) << 3),
                  (char*)Ws[buf] + chunk * 1024);
        }
    };

    stage(0, 0);
    const int NIT = K / BK;
    for (int it = 0; it < NIT; it++) {
        __syncthreads();                       // drains async loads of buf it&1
        if (it + 1 < NIT) stage((it + 1) & 1, (it + 1) * BK);
        const char* Ab = (const char*)As[it & 1];
        const char* Wb = (const char*)Ws[it & 1];
#pragma unroll
        for (int ks = 0; ks < BK / 32; ks++) {
            short8 af[4], wf[NI];
            const int dblk = ks * 4 + quad;
#pragma unroll
            for (int mi = 0; mi < 4; mi++) {
                int row = wm + mi * 16 + l15;
                af[mi] = *(const short8*)(Ab + row * (BK * 2) + ((dblk ^ (row & (UPR - 1))) << 4));
            }
#pragma unroll
            for (int ni = 0; ni < NI; ni++) {
                int row = wn + ni * 16 + l15;
                wf[ni] = *(const short8*)(Wb + row * (BK * 2) + ((dblk ^ (row & (UPR - 1))) << 4));
            }
#pragma unroll
            for (int mi = 0; mi < 4; mi++)
#pragma unroll
                for (int ni = 0; ni < NI; ni++)
                    acc[mi][ni] = __builtin_amdgcn_mfma_f32_16x16x32_bf16(
                        af[mi], wf[ni], acc[mi][ni], 0, 0, 0);
        }
    }
    if (vt && n0 >= 1024) {
        // V-projection epilogue: write transposed into paired-chunk Vt layout
#pragma unroll
        for (int ni = 0; ni < NI; ni++) {
            int n = n0 + wn + ni * 16 + l15;
            int d = n - 1024, h = d >> 6, dd = d & 63;
            float bz = bias[n];
#pragma unroll
            for (int mi = 0; mi < 4; mi++) {
                int mbase = m0 + wm + mi * 16 + quad * 4;   // 4 consecutive s
                int b = mbase >> 10, s = mbase & 1023;
                int tile = s >> 6, j = (s & 63) >> 2;       // chunk index 0..15
                size_t off = ((size_t)(b * NH + h) * HD + dd) * SEQ
                           + tile * 64 + (j & 7) * 8 + (j >> 3) * 4;
                short4v pk;
#pragma unroll
                for (int r = 0; r < 4; r++) pk[r] = f2bf(acc[mi][ni][r] + bz);
                *(short4v*)(vt + off) = pk;
            }
        }
    } else {
#pragma unroll
        for (int ni = 0; ni < NI; ni++) {
            int n = n0 + wn + ni * 16 + l15;
            float bz = bias[n];
#pragma unroll
            for (int mi = 0; mi < 4; mi++) {
#pragma unroll
                for (int r = 0; r < 4; r++) {
                    int m = m0 + wm + mi * 16 + quad * 4 + r;
                    float v = acc[mi][ni][r] + bz;
                    if (relu) v = fmaxf(v, 0.f);
                    C[(size_t)m * N + n] = f2bf(v);
                }
            }
        }
    }
}

// ---------------------------------------------------------------------------
// MFMA flash attention (unchanged from R7 — control).
#define EXP2SC 0.18033688011112042f   /* 0.125 * log2(e) */
__global__ __launch_bounds__(256, 4)
void attn_mfma(const short* __restrict__ qkv, const short* __restrict__ vt,
               const u64* __restrict__ maskS, const u64* __restrict__ maskL,
               const u64* __restrict__ maskG, short* __restrict__ out) {
    const int tid = threadIdx.x;
    const int w = tid >> 6, lane = tid & 63, l15 = lane & 15, quad = lane >> 4;
    const int p = blockIdx.x;
    const int g_ = (p & 7) + 8 * (p >> 7);          // (b,h) group, XCD-swizzled
    const int qt = (p >> 3) & 15;
    const int b = g_ >> 3, h = g_ & 7;
    const int q = qt * 64 + w * 16 + l15;

    __shared__ __align__(16) short Ks[128 * 64];
    __shared__ __align__(16) short Vs[128 * 64];

    short8 qf[2];
    {
        const short* qrow = qkv + ((size_t)(b * SEQ + q) * 1536) + h * 64;
#pragma unroll
        for (int ks = 0; ks < 2; ks++)
            qf[ks] = *(const short8*)(qrow + ks * 32 + quad * 8);
    }
    const u64* mrow = (h < 4) ? (maskS + ((size_t)b * SEQ + q) * 16)
                   : (h < 6) ? (maskL + ((size_t)b * SEQ + q) * 16)
                   :           (maskG + (size_t)b * 16);

    f32x4 of[4];
#pragma unroll
    for (int mt = 0; mt < 4; mt++) of[mt] = (f32x4){0.f, 0.f, 0.f, 0.f};
    float lsum = 0.f;

    const int r_in = lane >> 3, c8 = lane & 7;
    const int swz = (c8 ^ r_in) << 3;
    const short* kp = qkv + ((size_t)b * SEQ + r_in) * 1536 + 512 + h * 64 + swz;
    const short* vp = vt + ((size_t)((b * NH + h) * HD) + r_in) * SEQ + swz;
    const int fsw = (l15 & 7);

    for (int kt = 0; kt < SEQ; kt += 128) {
#pragma unroll
        for (int rep = 0; rep < 4; rep++) {
            int c = rep * 4 + w;
            gll16(kp + (size_t)(kt + c * 8) * 1536, (char*)Ks + c * 1024);
        }
#pragma unroll
        for (int rep = 0; rep < 4; rep++) {
            int v = rep * 4 + w;
            gll16(vp + (size_t)((v & 7) * 8) * SEQ + kt + (v >> 3) * 64,
                  (char*)Vs + v * 1024);
        }
        __syncthreads();

#pragma unroll
        for (int t = 0; t < 2; t++) {
            f32x4 sa[4];
#pragma unroll
            for (int g = 0; g < 4; g++) sa[g] = (f32x4){0.f, 0.f, 0.f, 0.f};
#pragma unroll
            for (int ks = 0; ks < 2; ks++) {
                const int dblk = ks * 4 + quad;
#pragma unroll
                for (int g = 0; g < 4; g++) {
                    int row = t * 64 + g * 16 + l15;
                    short8 kf = *(const short8*)((const char*)Ks + row * 128 + ((dblk ^ fsw) << 4));
                    sa[g] = __builtin_amdgcn_mfma_f32_16x16x32_bf16(kf, qf[ks], sa[g], 0, 0, 0);
                }
            }
            u64 mw = mrow[(kt >> 6) + t];
            if ((q >> 6) == (kt >> 6) + t) mw |= 1ull << (q & 63);
            u64 mq = mw >> (quad * 4);
            unsigned mlo = (unsigned)mq, mhi = (unsigned)(mq >> 32);
            short4v pfrag[4];
#pragma unroll
            for (int g = 0; g < 4; g++) {
                unsigned mg = ((g & 2) ? mhi : mlo) >> ((g & 1) * 16);
                float pv[4];
#pragma unroll
                for (int r = 0; r < 4; r++) {
                    float bias = ((mg >> r) & 1u) ? 0.f : -1e9f;
                    pv[r] = exp2f(fmaf(sa[g][r], EXP2SC, bias));
                    lsum += pv[r];
                }
                uint2v pk;
                pk[0] = __builtin_amdgcn_perm(__float_as_uint(pv[1]), __float_as_uint(pv[0]), 0x07060302u);
                pk[1] = __builtin_amdgcn_perm(__float_as_uint(pv[3]), __float_as_uint(pv[2]), 0x07060302u);
                pfrag[g] = __builtin_bit_cast(short4v, pk);
            }
#pragma unroll
            for (int g01 = 0; g01 < 2; g01++) {
                const int u = g01 * 4 + quad;
#pragma unroll
                for (int mt = 0; mt < 4; mt++) {
                    int row = mt * 16 + l15;
                    short8 vv = *(const short8*)((const char*)Vs + t * 8192 + row * 128 + ((u ^ fsw) << 4));
                    short4v vlo = {vv[0], vv[1], vv[2], vv[3]};
                    short4v vhi = {vv[4], vv[5], vv[6], vv[7]};
                    of[mt] = __builtin_amdgcn_mfma_f32_16x16x16bf16_1k(vlo, pfrag[g01], of[mt], 0, 0, 0);
                    of[mt] = __builtin_amdgcn_mfma_f32_16x16x16bf16_1k(vhi, pfrag[g01 + 2], of[mt], 0, 0, 0);
                }
            }
        }
        __syncthreads();
    }
    lsum += __shfl_xor(lsum, 16);
    lsum += __shfl_xor(lsum, 32);
    float inv = 1.f / lsum;
#pragma unroll
    for (int mt = 0; mt < 4; mt++) {
        short4v pk;
#pragma unroll
        for (int r = 0; r < 4; r++) pk[r] = f2bf(of[mt][r] * inv);
        *(short4v*)(out + ((size_t)(b * SEQ + q) * HDIM) + h * 64 + mt * 16 + quad * 4) = pk;
    }
}

// ---------------------------------------------------------------------------
// y = LN(x + r)*g + b, rows of 512. One wave per row (lane holds 8 elems).
__global__ __launch_bounds__(256) void ln_bf16(const short* __restrict__ x,
                                               const short* __restrict__ r,
                                               const float* __restrict__ g,
                                               const float* __restrict__ b,
                                               short* __restrict__ y) {
    const int wv = threadIdx.x >> 6, lane = threadIdx.x & 63;
    const size_t row = (size_t)blockIdx.x * 4 + wv;
    const size_t base = row * HDIM + lane * 8;
    short8 xv = *(const short8*)(x + base);
    float v[8];
#pragma unroll
    for (int i = 0; i < 8; i++) v[i] = bf2f(xv[i]);
    if (r) {
        short8 rv = *(const short8*)(r + base);
#pragma unroll
        for (int i = 0; i < 8; i++) v[i] += bf2f(rv[i]);
    }
    float s = 0.f, ss = 0.f;
#pragma unroll
    for (int i = 0; i < 8; i++) { s += v[i]; ss += v[i] * v[i]; }
#pragma unroll
    for (int off = 1; off < 64; off <<= 1) {
        s  += __shfl_xor(s, off);
        ss += __shfl_xor(ss, off);
    }
    const float mean = s * (1.f / HDIM);
    const float var  = ss * (1.f / HDIM) - mean * mean;
    const float inv  = rsqrtf(var + EPS);
    f32x4 g0 = *(const f32x4*)(g + lane * 8), g1 = *(const f32x4*)(g + lane * 8 + 4);
    f32x4 b0 = *(const f32x4*)(b + lane * 8), b1 = *(const f32x4*)(b + lane * 8 + 4);
    short8 o;
#pragma unroll
    for (int i = 0; i < 4; i++) o[i]     = f2bf((v[i]     - mean) * inv * g0[i] + b0[i]);
#pragma unroll
    for (int i = 0; i < 4; i++) o[i + 4] = f2bf((v[i + 4] - mean) * inv * g1[i] + b1[i]);
    *(short8*)(y + base) = o;
}

// ---------------------------------------------------------------------------
__global__ __launch_bounds__(256) void final_bn(const short* __restrict__ X,
                                                const float* __restrict__ g,
                                                const float* __restrict__ bb,
                                                float* __restrict__ out) {
    int h = blockIdx.x * 256 + threadIdx.x;
    if (h >= HDIM) return;
    float vals[BATCH];
    float m = 0.f;
#pragma unroll
    for (int b = 0; b < BATCH; b++) {
        vals[b] = bf2f(X[(size_t)b * SEQ * HDIM + h]);
        m += vals[b];
    }
    m *= (1.f / BATCH);
    float v = 0.f;
#pragma unroll
    for (int b = 0; b < BATCH; b++) { float d = vals[b] - m; v += d * d; }
    v *= (1.f / BATCH);
    float inv = rsqrtf(v + EPS);
#pragma unroll
    for (int b = 0; b < BATCH; b++)
        out[b * HDIM + h] = (vals[b] - m) * inv * g[h] + bb[h];
}

// ---------------------------------------------------------------------------
extern "C" void kernel_launch(void* const* d_in, const int* in_sizes, int n_in,
                              void* d_out, int out_size, void* d_ws, size_t ws_size,
                              hipStream_t stream) {
    const float* nodes      = (const float*)d_in[0];
    const int*   dist       = (const int*)  d_in[1];
    const float* dense_w    = (const float*)d_in[2];
    const float* dense_b    = (const float*)d_in[3];
    const float* dense_ln_g = (const float*)d_in[4];
    const float* dense_ln_b = (const float*)d_in[5];
    const float* qkv_w      = (const float*)d_in[6];
    const float* qkv_b      = (const float*)d_in[7];
    const float* out_w      = (const float*)d_in[8];
    const float* out_b      = (const float*)d_in[9];
    const float* ln1_g      = (const float*)d_in[10];
    const float* ln1_b      = (const float*)d_in[11];
    const float* ffn_w1     = (const float*)d_in[12];
    const float* ffn_b1     = (const float*)d_in[13];
    const float* ffn_w2     = (const float*)d_in[14];
    const float* ffn_b2     = (const float*)d_in[15];
    const float* ln2_g      = (const float*)d_in[16];
    const float* ln2_b      = (const float*)d_in[17];
    const float* bn_g       = (const float*)d_in[18];
    const float* bn_b       = (const float*)d_in[19];
    float* out = (float*)d_out;

    const int M = BATCH * SEQ;                         // 8192
    const size_t MB = 1024 * 1024;
    char* ws = (char*)d_ws;
    short* Wd   = (short*)(ws + 0 * MB);
    short* Wqkv = (short*)(ws + 1 * MB);
    short* Wo   = (short*)(ws + 9 * MB);
    short* W1   = (short*)(ws + 13 * MB);
    short* W2   = (short*)(ws + 18 * MB);
    u64*   mS   = (u64*)(ws + 23 * MB);
    u64*   mL   = (u64*)(ws + 24 * MB);
    u64*   mG   = (u64*)(ws + 25 * MB);
    short* X    = (short*)(ws + 26 * MB);
    short* QKV  = (short*)(ws + 34 * MB);
    short* Vt   = (short*)(ws + 58 * MB);
    short* AT   = (short*)(ws + 66 * MB);
    short* O2   = (short*)(ws + 74 * MB);
    short* XT   = QKV;
    short* F1   = QKV;
    short* F2   = AT;

    cvt_all<<<CVT_TOT / 1024, 256, 0, stream>>>(dense_w, Wd, qkv_w, Wqkv,
                                                out_w, Wo, ffn_w1, W1, ffn_w2, W2);
    transpose_nodes<<<(SEQ * BATCH * IDIM) / 1024, 256, 0, stream>>>(nodes, XT);
    build_masks<<<(BATCH * SEQ * 16) / 256, 256, 0, stream>>>(dist, mS, mL, mG);

    gemm_bf16<64, 64><<<dim3(HDIM / 128, M / 64), 256, 0, stream>>>(
        XT, Wd, dense_b, O2, nullptr, M, HDIM, IDIM, 0);
    ln_bf16<<<M / 4, 256, 0, stream>>>(O2, nullptr, dense_ln_g, dense_ln_b, X);

    for (int l = 0; l < LAYERS; l++) {
        const short* wqkv = Wqkv + (size_t)l * 3 * HDIM * HDIM;
        const float* bqkv = qkv_b + (size_t)l * 3 * HDIM;
        const short* wo   = Wo + (size_t)l * HDIM * HDIM;
        const float* bo   = out_b + (size_t)l * HDIM;
        const short* w1   = W1 + (size_t)l * FF * HDIM;
        const float* b1   = ffn_b1 + (size_t)l * FF;
        const short* w2   = W2 + (size_t)l * HDIM * FF;
        const float* b2   = ffn_b2 + (size_t)l * HDIM;

        gemm_bf16<64, 64><<<dim3(3 * HDIM / 128, M / 64), 256, 0, stream>>>(
            X, wqkv, bqkv, QKV, Vt, M, 3 * HDIM, HDIM, 0);
        attn_mfma<<<1024, 256, 0, stream>>>(QKV, Vt, mS, mL, mG, AT);
        gemm_bf16<64, 64><<<dim3(HDIM / 128, M / 64), 256, 0, stream>>>(
            AT, wo, bo, O2, nullptr, M, HDIM, HDIM, 0);
        ln_bf16<<<M / 4, 256, 0, stream>>>(X, O2, ln1_g + l * HDIM, ln1_b + l * HDIM, X);
        gemm_bf16<64, 64><<<dim3(FF / 128, M / 64), 256, 0, stream>>>(
            X, w1, b1, F1, nullptr, M, FF, HDIM, 1);
        gemm_bf16<64, 64><<<dim3(HDIM / 128, M / 64), 256, 0, stream>>>(
            F1, w2, b2, F2, nullptr, M, HDIM, FF, 0);
        ln_bf16<<<M / 4, 256, 0, stream>>>(X, F2, ln2_g + l * HDIM, ln2_b + l * HDIM, X);
    }
    final_bn<<<(HDIM + 255) / 256, 256, 0, stream>>>(X, bn_g, bn_b, out);
}

// Round 10
// 610.597 us; speedup vs baseline: 1.0723x; 1.0723x over previous
//
#include <hip/hip_runtime.h>
#include <hip/hip_bf16.h>
#include <math.h>

#define LAYERS 4
#define IDIM 256
#define HDIM 512
#define NH 8
#define HD 64
#define FF 1024
#define SEQ 1024
#define BATCH 8
#define EPS 1e-5f

typedef __attribute__((ext_vector_type(8))) short short8;
typedef __attribute__((ext_vector_type(4))) short short4v;
typedef __attribute__((ext_vector_type(4))) float f32x4;
typedef __attribute__((ext_vector_type(4))) int int4v;
typedef __attribute__((ext_vector_type(4))) unsigned int uint4v;
typedef unsigned long long u64;

// fp32 -> bf16 (RNE) on raw bits
__device__ __forceinline__ short f2bf(float f) {
    unsigned u = __float_as_uint(f);
    u = (u + 0x7FFFu + ((u >> 16) & 1u)) >> 16;
    return (short)u;
}
__device__ __forceinline__ float bf2f(short s) {
    return __uint_as_float(((unsigned)(unsigned short)s) << 16);
}
__device__ __forceinline__ void gll16(const void* g, void* l) {
    __builtin_amdgcn_global_load_lds(
        (const __attribute__((address_space(1))) unsigned int*)g,
        (__attribute__((address_space(3))) unsigned int*)l, 16, 0, 0);
}
// raw v_exp_f32 (2^x); exp2f may expand to a libm sequence
__device__ __forceinline__ float fexp2(float x) {
#if __has_builtin(__builtin_amdgcn_exp2f)
    return __builtin_amdgcn_exp2f(x);
#else
    return exp2f(x);
#endif
}

// ---------------------------------------------------------------------------
// merged prep: weight cvt (8320 blocks) + nodes transpose (2048) + masks (512)
#define CVT_P0 131072u
#define CVT_P1 3276800u
#define CVT_P2 4325376u
#define CVT_P3 6422528u
#define CVT_TOT 8519680u
__global__ __launch_bounds__(256) void prep_all(
    const float* __restrict__ s0, short* __restrict__ d0,
    const float* __restrict__ s1, short* __restrict__ d1,
    const float* __restrict__ s2, short* __restrict__ d2,
    const float* __restrict__ s3, short* __restrict__ d3,
    const float* __restrict__ s4, short* __restrict__ d4,
    const float* __restrict__ nodes, short* __restrict__ xt,
    const int* __restrict__ dist, u64* __restrict__ mS,
    u64* __restrict__ mL, u64* __restrict__ mG) {
    int blk = blockIdx.x;
    if (blk < 8320) {                       // weight fp32->bf16
        size_t i = ((size_t)blk * 256 + threadIdx.x) * 4;
        const float* s; short* d; size_t off;
        if (i < CVT_P0)      { s = s0; d = d0; off = i; }
        else if (i < CVT_P1) { s = s1; d = d1; off = i - CVT_P0; }
        else if (i < CVT_P2) { s = s2; d = d2; off = i - CVT_P1; }
        else if (i < CVT_P3) { s = s3; d = d3; off = i - CVT_P2; }
        else                 { s = s4; d = d4; off = i - CVT_P3; }
        f32x4 f = *(const f32x4*)(s + off);
        short4v o = {f2bf(f[0]), f2bf(f[1]), f2bf(f[2]), f2bf(f[3])};
        *(short4v*)(d + off) = o;
    } else if (blk < 8320 + 2048) {         // nodes (S,B,I) -> (B*S,I) bf16
        size_t idx = ((size_t)(blk - 8320) * 256 + threadIdx.x) * 4;
        int i  = idx & (IDIM - 1);
        int sb = idx >> 8;
        int b  = sb & (BATCH - 1);
        int s  = sb >> 3;
        f32x4 f = *(const f32x4*)(nodes + idx);
        short4v o = {f2bf(f[0]), f2bf(f[1]), f2bf(f[2]), f2bf(f[3])};
        *(short4v*)(xt + ((size_t)b * SEQ + s) * IDIM + i) = o;
    } else {                                // per-(b,q) 64-bit key masks
        int t = (blk - 10368) * 256 + threadIdx.x;
        int w = t & 15, q = (t >> 4) & 1023, b = t >> 14;
        const int4v* dp = (const int4v*)(dist + ((size_t)b * SEQ + q) * SEQ + w * 64);
        u64 bs = 0, bl = 0;
#pragma unroll
        for (int i = 0; i < 16; i++) {
            int4v d = dp[i];
#pragma unroll
            for (int j = 0; j < 4; j++) {
                bs |= (u64)(d[j] == 1) << (i * 4 + j);
                bl |= (u64)(d[j] >= 1) << (i * 4 + j);
            }
        }
        mS[((size_t)b * SEQ + q) * 16 + w] = bs;
        mL[((size_t)b * SEQ + q) * 16 + w] = bl;
        if (q == 0) mG[b * 16 + w] = bl;
    }
}

// ---------------------------------------------------------------------------
// bf16 MFMA GEMM (16x16x32), R7-proven structure. BM x 128 tile, K-step BK.
// If vt != null, column blocks with n0 >= 1024 (V-projection) are written as a
// PLAIN transpose into Vt (B,NH,HD,S) instead of C.
template<int BM, int BK>
__global__ __launch_bounds__(256, 2)
void gemm_bf16(const short* __restrict__ A, const short* __restrict__ W,
               const float* __restrict__ bias, short* __restrict__ C,
               short* __restrict__ vt, int M, int N, int K, int relu) {
    constexpr int UPR = BK / 8;        // 16B units per row
    constexpr int RPC = 512 / BK;      // rows per 1KB staging chunk
    __shared__ __align__(16) short As[BM * BK];
    __shared__ __align__(16) short Ws[128 * BK];
    const int tid = threadIdx.x;
    const int w = tid >> 6, lane = tid & 63;
    const int l15 = lane & 15, quad = lane >> 4;
    const int m0 = blockIdx.y * BM, n0 = blockIdx.x * 128;

    constexpr int NI = (BM == 128) ? 4 : 2;
    const int wm = (BM == 128) ? (w >> 1) * 64 : 0;
    const int wn = (BM == 128) ? (w & 1) * 64 : w * 32;

    f32x4 acc[4][NI];
#pragma unroll
    for (int mi = 0; mi < 4; mi++)
#pragma unroll
        for (int ni = 0; ni < NI; ni++) acc[mi][ni] = (f32x4){0.f, 0.f, 0.f, 0.f};

    const int r_in = (BK == 64) ? (lane >> 3) : (lane >> 4);
    const int c8   = lane & (UPR - 1);

    for (int k0 = 0; k0 < K; k0 += BK) {
#pragma unroll
        for (int rep = 0; rep < BM * BK / 2048; rep++) {
            int chunk = rep * 4 + w;
            int row = chunk * RPC + r_in;
            const short* src = A + (size_t)(m0 + row) * K + k0 + ((c8 ^ (row & (UPR - 1))) << 3);
            gll16(src, (char*)As + chunk * 1024);
        }
#pragma unroll
        for (int rep = 0; rep < 128 * BK / 2048; rep++) {
            int chunk = rep * 4 + w;
            int row = chunk * RPC + r_in;
            const short* src = W + (size_t)(n0 + row) * K + k0 + ((c8 ^ (row & (UPR - 1))) << 3);
            gll16(src, (char*)Ws + chunk * 1024);
        }
        __syncthreads();
#pragma unroll
        for (int ks = 0; ks < BK / 32; ks++) {
            short8 af[4], wf[NI];
            const int dblk = ks * 4 + quad;
#pragma unroll
            for (int mi = 0; mi < 4; mi++) {
                int row = wm + mi * 16 + l15;
                af[mi] = *(const short8*)((const char*)As + row * (BK * 2) + ((dblk ^ (row & (UPR - 1))) << 4));
            }
#pragma unroll
            for (int ni = 0; ni < NI; ni++) {
                int row = wn + ni * 16 + l15;
                wf[ni] = *(const short8*)((const char*)Ws + row * (BK * 2) + ((dblk ^ (row & (UPR - 1))) << 4));
            }
#pragma unroll
            for (int mi = 0; mi < 4; mi++)
#pragma unroll
                for (int ni = 0; ni < NI; ni++)
                    acc[mi][ni] = __builtin_amdgcn_mfma_f32_16x16x32_bf16(
                        af[mi], wf[ni], acc[mi][ni], 0, 0, 0);
        }
        __syncthreads();
    }
    if (vt && n0 >= 1024) {
        // V-projection epilogue: plain transpose into Vt (B,NH,HD,S)
#pragma unroll
        for (int ni = 0; ni < NI; ni++) {
            int n = n0 + wn + ni * 16 + l15;
            int d = n - 1024, h = d >> 6, dd = d & 63;
            float bz = bias[n];
#pragma unroll
            for (int mi = 0; mi < 4; mi++) {
                int mbase = m0 + wm + mi * 16 + quad * 4;   // 4 consecutive s
                int b = mbase >> 10, s = mbase & 1023;
                size_t off = ((size_t)(b * NH + h) * HD + dd) * SEQ + s;
                short4v pk;
#pragma unroll
                for (int r = 0; r < 4; r++) pk[r] = f2bf(acc[mi][ni][r] + bz);
                *(short4v*)(vt + off) = pk;
            }
        }
    } else {
#pragma unroll
        for (int ni = 0; ni < NI; ni++) {
            int n = n0 + wn + ni * 16 + l15;
            float bz = bias[n];
#pragma unroll
            for (int mi = 0; mi < 4; mi++) {
#pragma unroll
                for (int r = 0; r < 4; r++) {
                    int m = m0 + wm + mi * 16 + quad * 4 + r;
                    float v = acc[mi][ni][r] + bz;
                    if (relu) v = fmaxf(v, 0.f);
                    C[(size_t)m * N + n] = f2bf(v);
                }
            }
        }
    }
}

// ---------------------------------------------------------------------------
// MFMA flash attention. Key-permuted K staging makes S^T's C-layout directly a
// K=32 B-frag for PV (16x16x32, full-rate, zero shuffles): staged physical row
// p holds logical key L(p) with bit permutation out5=b5,out4..3=b3b2,out2=b4,
// out1..0=b1b0. Softmax/lsum are permutation-invariant; mask bits extracted at
// permuted positions; V needs no permutation. 128-key tile per barrier pair.
#define EXP2SC 0.18033688011112042f   /* 0.125 * log2(e) */
__global__ __launch_bounds__(256, 4)
void attn_mfma(const short* __restrict__ qkv, const short* __restrict__ vt,
               const u64* __restrict__ maskS, const u64* __restrict__ maskL,
               const u64* __restrict__ maskG, short* __restrict__ out) {
    const int tid = threadIdx.x;
    const int w = tid >> 6, lane = tid & 63, l15 = lane & 15, quad = lane >> 4;
    const int p = blockIdx.x;
    const int g_ = (p & 7) + 8 * (p >> 7);          // (b,h) group, XCD-swizzled
    const int qt = (p >> 3) & 15;
    const int b = g_ >> 3, h = g_ & 7;
    const int q = qt * 64 + w * 16 + l15;

    __shared__ __align__(16) short Ks[128 * 64];    // 128 keys (permuted) x 64 d
    __shared__ __align__(16) short Vs[128 * 64];    // 2 halves: 64 d x 64 keys

    short8 qf[2];
    {
        const short* qrow = qkv + ((size_t)(b * SEQ + q) * 1536) + h * 64;
#pragma unroll
        for (int ks = 0; ks < 2; ks++)
            qf[ks] = *(const short8*)(qrow + ks * 32 + quad * 8);
    }
    const u64* mrow = (h < 4) ? (maskS + ((size_t)b * SEQ + q) * 16)
                   : (h < 6) ? (maskL + ((size_t)b * SEQ + q) * 16)
                   :           (maskG + (size_t)b * 16);

    f32x4 of[4];
#pragma unroll
    for (int mt = 0; mt < 4; mt++) of[mt] = (f32x4){0.f, 0.f, 0.f, 0.f};
    float ls0 = 0.f, ls1 = 0.f;

    const int r_in = lane >> 3, c8 = lane & 7;
    const int swz = (c8 ^ r_in) << 3;   // chunk-invariant staging swizzle
    const short* kbase = qkv + ((size_t)b * SEQ) * 1536 + 512 + h * 64 + swz;
    const short* vp = vt + ((size_t)((b * NH + h) * HD) + r_in) * SEQ + swz;
    const int fsw = (l15 & 7);

    for (int kt = 0; kt < SEQ; kt += 128) {
#pragma unroll
        for (int rep = 0; rep < 4; rep++) {         // K: permuted rows
            int c = rep * 4 + w;
            int pr = c * 8 + r_in;                  // physical staged row
            int pt = pr & 63;
            int key = (pr & 64) | (pt & 32) | (((pt >> 2) & 3) << 3)
                    | (((pt >> 4) & 1) << 2) | (pt & 3);
            gll16(kbase + (size_t)(kt + key) * 1536, (char*)Ks + c * 1024);
        }
#pragma unroll
        for (int rep = 0; rep < 4; rep++) {         // V: plain, 2 halves x 8
            int v = rep * 4 + w;
            gll16(vp + (size_t)((v & 7) * 8) * SEQ + kt + (v >> 3) * 64,
                  (char*)Vs + v * 1024);
        }
        __syncthreads();

#pragma unroll
        for (int t = 0; t < 2; t++) {
            // S^T sub-tile (64 permuted keys x 16 q)
            f32x4 sa[4];
#pragma unroll
            for (int g = 0; g < 4; g++) sa[g] = (f32x4){0.f, 0.f, 0.f, 0.f};
#pragma unroll
            for (int ks = 0; ks < 2; ks++) {
                const int dblk = ks * 4 + quad;
#pragma unroll
                for (int g = 0; g < 4; g++) {
                    int row = t * 64 + g * 16 + l15;
                    short8 kf = *(const short8*)((const char*)Ks + row * 128 + ((dblk ^ fsw) << 4));
                    sa[g] = __builtin_amdgcn_mfma_f32_16x16x32_bf16(kf, qf[ks], sa[g], 0, 0, 0);
                }
            }
            // masked softmax numerator (max-free); logical bitpos for slot
            // (g,quad,r) is quad*8 + (g>>1)*32 + (g&1)*4 + r
            u64 mw = mrow[(kt >> 6) + t];
            if ((q >> 6) == (kt >> 6) + t) mw |= 1ull << (q & 63);
            u64 mq2 = mw >> (quad * 8);
            unsigned mlo = (unsigned)mq2, mhi = (unsigned)(mq2 >> 32);
            float pv[4][4];
#pragma unroll
            for (int g = 0; g < 4; g++) {
                unsigned mg = ((g & 2) ? mhi : mlo) >> ((g & 1) * 4);
#pragma unroll
                for (int r = 0; r < 4; r++) {
                    float e = fexp2(sa[g][r] * EXP2SC);
                    e = ((mg >> r) & 1u) ? e : 0.f;
                    pv[g][r] = e;
                    if (g & 1) ls1 += e; else ls0 += e;
                }
            }
            // pack C reg-pairs directly into K=32 B-frags (no shuffles)
            short8 pfrag[2];
#pragma unroll
            for (int g32 = 0; g32 < 2; g32++) {
                uint4v pk;
                pk[0] = __builtin_amdgcn_perm(__float_as_uint(pv[2 * g32][1]),
                                              __float_as_uint(pv[2 * g32][0]), 0x07060302u);
                pk[1] = __builtin_amdgcn_perm(__float_as_uint(pv[2 * g32][3]),
                                              __float_as_uint(pv[2 * g32][2]), 0x07060302u);
                pk[2] = __builtin_amdgcn_perm(__float_as_uint(pv[2 * g32 + 1][1]),
                                              __float_as_uint(pv[2 * g32 + 1][0]), 0x07060302u);
                pk[3] = __builtin_amdgcn_perm(__float_as_uint(pv[2 * g32 + 1][3]),
                                              __float_as_uint(pv[2 * g32 + 1][2]), 0x07060302u);
                pfrag[g32] = __builtin_bit_cast(short8, pk);
            }
            // O^T += V^T . P^T  (16x16x32, 8 MFMAs per sub-tile)
#pragma unroll
            for (int g32 = 0; g32 < 2; g32++) {
                const int u = g32 * 4 + quad;
#pragma unroll
                for (int mt = 0; mt < 4; mt++) {
                    int row = mt * 16 + l15;
                    short8 vf = *(const short8*)((const char*)Vs + t * 8192 + row * 128 + ((u ^ fsw) << 4));
                    of[mt] = __builtin_amdgcn_mfma_f32_16x16x32_bf16(vf, pfrag[g32], of[mt], 0, 0, 0);
                }
            }
        }
        __syncthreads();
    }
    float lsum = ls0 + ls1;
    lsum += __shfl_xor(lsum, 16);
    lsum += __shfl_xor(lsum, 32);
    float inv = 1.f / lsum;              // diagonal always allowed -> lsum > 0
#pragma unroll
    for (int mt = 0; mt < 4; mt++) {
        short4v pk;
#pragma unroll
        for (int r = 0; r < 4; r++) pk[r] = f2bf(of[mt][r] * inv);
        *(short4v*)(out + ((size_t)(b * SEQ + q) * HDIM) + h * 64 + mt * 16 + quad * 4) = pk;
    }
}

// ---------------------------------------------------------------------------
// y = LN(x + r)*g + b, rows of 512. One wave per row (lane holds 8 elems).
__global__ __launch_bounds__(256) void ln_bf16(const short* __restrict__ x,
                                               const short* __restrict__ r,
                                               const float* __restrict__ g,
                                               const float* __restrict__ b,
                                               short* __restrict__ y) {
    const int wv = threadIdx.x >> 6, lane = threadIdx.x & 63;
    const size_t row = (size_t)blockIdx.x * 4 + wv;
    const size_t base = row * HDIM + lane * 8;
    short8 xv = *(const short8*)(x + base);
    float v[8];
#pragma unroll
    for (int i = 0; i < 8; i++) v[i] = bf2f(xv[i]);
    if (r) {
        short8 rv = *(const short8*)(r + base);
#pragma unroll
        for (int i = 0; i < 8; i++) v[i] += bf2f(rv[i]);
    }
    float s = 0.f, ss = 0.f;
#pragma unroll
    for (int i = 0; i < 8; i++) { s += v[i]; ss += v[i] * v[i]; }
#pragma unroll
    for (int off = 1; off < 64; off <<= 1) {
        s  += __shfl_xor(s, off);
        ss += __shfl_xor(ss, off);
    }
    const float mean = s * (1.f / HDIM);
    const float var  = ss * (1.f / HDIM) - mean * mean;
    const float inv  = rsqrtf(var + EPS);
    f32x4 g0 = *(const f32x4*)(g + lane * 8), g1 = *(const f32x4*)(g + lane * 8 + 4);
    f32x4 b0 = *(const f32x4*)(b + lane * 8), b1 = *(const f32x4*)(b + lane * 8 + 4);
    short8 o;
#pragma unroll
    for (int i = 0; i < 4; i++) o[i]     = f2bf((v[i]     - mean) * inv * g0[i] + b0[i]);
#pragma unroll
    for (int i = 0; i < 4; i++) o[i + 4] = f2bf((v[i + 4] - mean) * inv * g1[i] + b1[i]);
    *(short8*)(y + base) = o;
}

// ---------------------------------------------------------------------------
__global__ __launch_bounds__(256) void final_bn(const short* __restrict__ X,
                                                const float* __restrict__ g,
                                                const float* __restrict__ bb,
                                                float* __restrict__ out) {
    int h = blockIdx.x * 256 + threadIdx.x;
    if (h >= HDIM) return;
    float vals[BATCH];
    float m = 0.f;
#pragma unroll
    for (int b = 0; b < BATCH; b++) {
        vals[b] = bf2f(X[(size_t)b * SEQ * HDIM + h]);
        m += vals[b];
    }
    m *= (1.f / BATCH);
    float v = 0.f;
#pragma unroll
    for (int b = 0; b < BATCH; b++) { float d = vals[b] - m; v += d * d; }
    v *= (1.f / BATCH);
    float inv = rsqrtf(v + EPS);
#pragma unroll
    for (int b = 0; b < BATCH; b++)
        out[b * HDIM + h] = (vals[b] - m) * inv * g[h] + bb[h];
}

// ---------------------------------------------------------------------------
extern "C" void kernel_launch(void* const* d_in, const int* in_sizes, int n_in,
                              void* d_out, int out_size, void* d_ws, size_t ws_size,
                              hipStream_t stream) {
    const float* nodes      = (const float*)d_in[0];
    const int*   dist       = (const int*)  d_in[1];
    const float* dense_w    = (const float*)d_in[2];
    const float* dense_b    = (const float*)d_in[3];
    const float* dense_ln_g = (const float*)d_in[4];
    const float* dense_ln_b = (const float*)d_in[5];
    const float* qkv_w      = (const float*)d_in[6];
    const float* qkv_b      = (const float*)d_in[7];
    const float* out_w      = (const float*)d_in[8];
    const float* out_b      = (const float*)d_in[9];
    const float* ln1_g      = (const float*)d_in[10];
    const float* ln1_b      = (const float*)d_in[11];
    const float* ffn_w1     = (const float*)d_in[12];
    const float* ffn_b1     = (const float*)d_in[13];
    const float* ffn_w2     = (const float*)d_in[14];
    const float* ffn_b2     = (const float*)d_in[15];
    const float* ln2_g      = (const float*)d_in[16];
    const float* ln2_b      = (const float*)d_in[17];
    const float* bn_g       = (const float*)d_in[18];
    const float* bn_b       = (const float*)d_in[19];
    float* out = (float*)d_out;

    const int M = BATCH * SEQ;                         // 8192
    const size_t MB = 1024 * 1024;
    char* ws = (char*)d_ws;
    short* Wd   = (short*)(ws + 0 * MB);
    short* Wqkv = (short*)(ws + 1 * MB);
    short* Wo   = (short*)(ws + 9 * MB);
    short* W1   = (short*)(ws + 13 * MB);
    short* W2   = (short*)(ws + 18 * MB);
    u64*   mS   = (u64*)(ws + 23 * MB);
    u64*   mL   = (u64*)(ws + 24 * MB);
    u64*   mG   = (u64*)(ws + 25 * MB);
    short* X    = (short*)(ws + 26 * MB);
    short* QKV  = (short*)(ws + 34 * MB);
    short* Vt   = (short*)(ws + 58 * MB);
    short* AT   = (short*)(ws + 66 * MB);
    short* O2   = (short*)(ws + 74 * MB);
    short* XT   = QKV;
    short* F1   = QKV;
    short* F2   = AT;

    prep_all<<<10880, 256, 0, stream>>>(dense_w, Wd, qkv_w, Wqkv, out_w, Wo,
                                        ffn_w1, W1, ffn_w2, W2,
                                        nodes, XT, dist, mS, mL, mG);

    gemm_bf16<64, 128><<<dim3(HDIM / 128, M / 64), 256, 0, stream>>>(
        XT, Wd, dense_b, O2, nullptr, M, HDIM, IDIM, 0);
    ln_bf16<<<M / 4, 256, 0, stream>>>(O2, nullptr, dense_ln_g, dense_ln_b, X);

    for (int l = 0; l < LAYERS; l++) {
        const short* wqkv = Wqkv + (size_t)l * 3 * HDIM * HDIM;
        const float* bqkv = qkv_b + (size_t)l * 3 * HDIM;
        const short* wo   = Wo + (size_t)l * HDIM * HDIM;
        const float* bo   = out_b + (size_t)l * HDIM;
        const short* w1   = W1 + (size_t)l * FF * HDIM;
        const float* b1   = ffn_b1 + (size_t)l * FF;
        const short* w2   = W2 + (size_t)l * HDIM * FF;
        const float* b2   = ffn_b2 + (size_t)l * HDIM;

        gemm_bf16<128, 64><<<dim3(3 * HDIM / 128, M / 128), 256, 0, stream>>>(
            X, wqkv, bqkv, QKV, Vt, M, 3 * HDIM, HDIM, 0);
        attn_mfma<<<1024, 256, 0, stream>>>(QKV, Vt, mS, mL, mG, AT);
        gemm_bf16<64, 128><<<dim3(HDIM / 128, M / 64), 256, 0, stream>>>(
            AT, wo, bo, O2, nullptr, M, HDIM, HDIM, 0);
        ln_bf16<<<M / 4, 256, 0, stream>>>(X, O2, ln1_g + l * HDIM, ln1_b + l * HDIM, X);
        gemm_bf16<128, 64><<<dim3(FF / 128, M / 128), 256, 0, stream>>>(
            X, w1, b1, F1, nullptr, M, FF, HDIM, 1);
        gemm_bf16<64, 128><<<dim3(HDIM / 128, M / 64), 256, 0, stream>>>(
            F1, w2, b2, F2, nullptr, M, HDIM, FF, 0);
        ln_bf16<<<M / 4, 256, 0, stream>>>(X, F2, ln2_g + l * HDIM, ln2_b + l * HDIM, X);
    }
    final_bn<<<(HDIM + 255) / 256, 256, 0, stream>>>(X, bn_g, bn_b, out);
}

// Round 11
// 579.581 us; speedup vs baseline: 1.1296x; 1.0535x over previous
//
#include <hip/hip_runtime.h>
#include <hip/hip_bf16.h>
#include <math.h>

#define LAYERS 4
#define IDIM 256
#define HDIM 512
#define NH 8
#define HD 64
#define FF 1024
#define SEQ 1024
#define BATCH 8
#define EPS 1e-5f

typedef __attribute__((ext_vector_type(8))) short short8;
typedef __attribute__((ext_vector_type(4))) short short4v;
typedef __attribute__((ext_vector_type(4))) float f32x4;
typedef __attribute__((ext_vector_type(4))) int int4v;
typedef __attribute__((ext_vector_type(4))) unsigned int uint4v;
typedef unsigned long long u64;

// fp32 -> bf16 (RNE) on raw bits
__device__ __forceinline__ short f2bf(float f) {
    unsigned u = __float_as_uint(f);
    u = (u + 0x7FFFu + ((u >> 16) & 1u)) >> 16;
    return (short)u;
}
__device__ __forceinline__ float bf2f(short s) {
    return __uint_as_float(((unsigned)(unsigned short)s) << 16);
}
__device__ __forceinline__ void gll16(const void* g, void* l) {
    __builtin_amdgcn_global_load_lds(
        (const __attribute__((address_space(1))) unsigned int*)g,
        (__attribute__((address_space(3))) unsigned int*)l, 16, 0, 0);
}
// raw v_exp_f32 (2^x); exp2f may expand to a libm sequence
__device__ __forceinline__ float fexp2(float x) {
#if __has_builtin(__builtin_amdgcn_exp2f)
    return __builtin_amdgcn_exp2f(x);
#else
    return exp2f(x);
#endif
}

// ---------------------------------------------------------------------------
// merged prep: weight cvt (8320 blocks) + nodes transpose (2048 blocks) +
// ballot-based mask build (8192 blocks, one per (b,q), coalesced dist reads).
#define CVT_P0 131072u
#define CVT_P1 3276800u
#define CVT_P2 4325376u
#define CVT_P3 6422528u
#define CVT_TOT 8519680u
#define PREP_W 8320
#define PREP_N 2048
__global__ __launch_bounds__(256) void prep_all(
    const float* __restrict__ s0, short* __restrict__ d0,
    const float* __restrict__ s1, short* __restrict__ d1,
    const float* __restrict__ s2, short* __restrict__ d2,
    const float* __restrict__ s3, short* __restrict__ d3,
    const float* __restrict__ s4, short* __restrict__ d4,
    const float* __restrict__ nodes, short* __restrict__ xt,
    const int* __restrict__ dist, u64* __restrict__ mS,
    u64* __restrict__ mL, u64* __restrict__ mG) {
    int blk = blockIdx.x;
    if (blk < PREP_W) {                     // weight fp32->bf16
        size_t i = ((size_t)blk * 256 + threadIdx.x) * 4;
        const float* s; short* d; size_t off;
        if (i < CVT_P0)      { s = s0; d = d0; off = i; }
        else if (i < CVT_P1) { s = s1; d = d1; off = i - CVT_P0; }
        else if (i < CVT_P2) { s = s2; d = d2; off = i - CVT_P1; }
        else if (i < CVT_P3) { s = s3; d = d3; off = i - CVT_P2; }
        else                 { s = s4; d = d4; off = i - CVT_P3; }
        f32x4 f = *(const f32x4*)(s + off);
        short4v o = {f2bf(f[0]), f2bf(f[1]), f2bf(f[2]), f2bf(f[3])};
        *(short4v*)(d + off) = o;
    } else if (blk < PREP_W + PREP_N) {     // nodes (S,B,I) -> (B*S,I) bf16
        size_t idx = ((size_t)(blk - PREP_W) * 256 + threadIdx.x) * 4;
        int i  = idx & (IDIM - 1);
        int sb = idx >> 8;
        int b  = sb & (BATCH - 1);
        int s  = sb >> 3;
        f32x4 f = *(const f32x4*)(nodes + idx);
        short4v o = {f2bf(f[0]), f2bf(f[1]), f2bf(f[2]), f2bf(f[3])};
        *(short4v*)(xt + ((size_t)b * SEQ + s) * IDIM + i) = o;
    } else {                                // ballot mask build, 1 blk per (b,q)
        int blk2 = blk - (PREP_W + PREP_N);
        int b = blk2 >> 10, q = blk2 & 1023;
        int wv = threadIdx.x >> 6, lane = threadIdx.x & 63;
        const int* dp = dist + ((size_t)b * SEQ + q) * SEQ;
        size_t mbase = ((size_t)b * SEQ + q) * 16;
#pragma unroll
        for (int it = 0; it < 4; it++) {
            int w64 = it * 4 + wv;
            int d = dp[w64 * 64 + lane];
            u64 bs = __ballot(d == 1);
            u64 bl = __ballot(d >= 1);
            if (lane == 0) {
                mS[mbase + w64] = bs;
                mL[mbase + w64] = bl;
                if (q == 0) mG[b * 16 + w64] = bl;
            }
        }
    }
}

// ---------------------------------------------------------------------------
// bf16 MFMA GEMM (16x16x32), R7-proven structure. BM x 128 tile, K-step BK.
// If vt != null, column blocks with n0 >= 1024 (V-projection) are written as a
// PLAIN transpose into Vt (B,NH,HD,S) instead of C.
template<int BM, int BK>
__global__ __launch_bounds__(256, 2)
void gemm_bf16(const short* __restrict__ A, const short* __restrict__ W,
               const float* __restrict__ bias, short* __restrict__ C,
               short* __restrict__ vt, int M, int N, int K, int relu) {
    constexpr int UPR = BK / 8;        // 16B units per row
    constexpr int RPC = 512 / BK;      // rows per 1KB staging chunk
    __shared__ __align__(16) short As[BM * BK];
    __shared__ __align__(16) short Ws[128 * BK];
    const int tid = threadIdx.x;
    const int w = tid >> 6, lane = tid & 63;
    const int l15 = lane & 15, quad = lane >> 4;
    const int m0 = blockIdx.y * BM, n0 = blockIdx.x * 128;

    constexpr int NI = (BM == 128) ? 4 : 2;
    const int wm = (BM == 128) ? (w >> 1) * 64 : 0;
    const int wn = (BM == 128) ? (w & 1) * 64 : w * 32;

    f32x4 acc[4][NI];
#pragma unroll
    for (int mi = 0; mi < 4; mi++)
#pragma unroll
        for (int ni = 0; ni < NI; ni++) acc[mi][ni] = (f32x4){0.f, 0.f, 0.f, 0.f};

    const int r_in = (BK == 64) ? (lane >> 3) : (lane >> 4);
    const int c8   = lane & (UPR - 1);

    for (int k0 = 0; k0 < K; k0 += BK) {
#pragma unroll
        for (int rep = 0; rep < BM * BK / 2048; rep++) {
            int chunk = rep * 4 + w;
            int row = chunk * RPC + r_in;
            const short* src = A + (size_t)(m0 + row) * K + k0 + ((c8 ^ (row & (UPR - 1))) << 3);
            gll16(src, (char*)As + chunk * 1024);
        }
#pragma unroll
        for (int rep = 0; rep < 128 * BK / 2048; rep++) {
            int chunk = rep * 4 + w;
            int row = chunk * RPC + r_in;
            const short* src = W + (size_t)(n0 + row) * K + k0 + ((c8 ^ (row & (UPR - 1))) << 3);
            gll16(src, (char*)Ws + chunk * 1024);
        }
        __syncthreads();
#pragma unroll
        for (int ks = 0; ks < BK / 32; ks++) {
            short8 af[4], wf[NI];
            const int dblk = ks * 4 + quad;
#pragma unroll
            for (int mi = 0; mi < 4; mi++) {
                int row = wm + mi * 16 + l15;
                af[mi] = *(const short8*)((const char*)As + row * (BK * 2) + ((dblk ^ (row & (UPR - 1))) << 4));
            }
#pragma unroll
            for (int ni = 0; ni < NI; ni++) {
                int row = wn + ni * 16 + l15;
                wf[ni] = *(const short8*)((const char*)Ws + row * (BK * 2) + ((dblk ^ (row & (UPR - 1))) << 4));
            }
#pragma unroll
            for (int mi = 0; mi < 4; mi++)
#pragma unroll
                for (int ni = 0; ni < NI; ni++)
                    acc[mi][ni] = __builtin_amdgcn_mfma_f32_16x16x32_bf16(
                        af[mi], wf[ni], acc[mi][ni], 0, 0, 0);
        }
        __syncthreads();
    }
    if (vt && n0 >= 1024) {
        // V-projection epilogue: plain transpose into Vt (B,NH,HD,S)
#pragma unroll
        for (int ni = 0; ni < NI; ni++) {
            int n = n0 + wn + ni * 16 + l15;
            int d = n - 1024, h = d >> 6, dd = d & 63;
            float bz = bias[n];
#pragma unroll
            for (int mi = 0; mi < 4; mi++) {
                int mbase = m0 + wm + mi * 16 + quad * 4;   // 4 consecutive s
                int b = mbase >> 10, s = mbase & 1023;
                size_t off = ((size_t)(b * NH + h) * HD + dd) * SEQ + s;
                short4v pk;
#pragma unroll
                for (int r = 0; r < 4; r++) pk[r] = f2bf(acc[mi][ni][r] + bz);
                *(short4v*)(vt + off) = pk;
            }
        }
    } else {
#pragma unroll
        for (int ni = 0; ni < NI; ni++) {
            int n = n0 + wn + ni * 16 + l15;
            float bz = bias[n];
#pragma unroll
            for (int mi = 0; mi < 4; mi++) {
#pragma unroll
                for (int r = 0; r < 4; r++) {
                    int m = m0 + wm + mi * 16 + quad * 4 + r;
                    float v = acc[mi][ni][r] + bz;
                    if (relu) v = fmaxf(v, 0.f);
                    C[(size_t)m * N + n] = f2bf(v);
                }
            }
        }
    }
}

// ---------------------------------------------------------------------------
// MFMA flash attention. Key-permuted K staging makes S^T's C-layout directly a
// K=32 B-frag for PV (16x16x32, full-rate, zero shuffles): staged physical row
// p holds logical key L(p) with bit permutation out5=b5,out4..3=b3b2,out2=b4,
// out1..0=b1b0. Softmax/lsum are permutation-invariant; mask bits extracted at
// permuted positions; V needs no permutation. 128-key tile per barrier pair.
#define EXP2SC 0.18033688011112042f   /* 0.125 * log2(e) */
__global__ __launch_bounds__(256, 4)
void attn_mfma(const short* __restrict__ qkv, const short* __restrict__ vt,
               const u64* __restrict__ maskS, const u64* __restrict__ maskL,
               const u64* __restrict__ maskG, short* __restrict__ out) {
    const int tid = threadIdx.x;
    const int w = tid >> 6, lane = tid & 63, l15 = lane & 15, quad = lane >> 4;
    const int p = blockIdx.x;
    const int g_ = (p & 7) + 8 * (p >> 7);          // (b,h) group, XCD-swizzled
    const int qt = (p >> 3) & 15;
    const int b = g_ >> 3, h = g_ & 7;
    const int q = qt * 64 + w * 16 + l15;

    __shared__ __align__(16) short Ks[128 * 64];    // 128 keys (permuted) x 64 d
    __shared__ __align__(16) short Vs[128 * 64];    // 2 halves: 64 d x 64 keys

    short8 qf[2];
    {
        const short* qrow = qkv + ((size_t)(b * SEQ + q) * 1536) + h * 64;
#pragma unroll
        for (int ks = 0; ks < 2; ks++)
            qf[ks] = *(const short8*)(qrow + ks * 32 + quad * 8);
    }
    const u64* mrow = (h < 4) ? (maskS + ((size_t)b * SEQ + q) * 16)
                   : (h < 6) ? (maskL + ((size_t)b * SEQ + q) * 16)
                   :           (maskG + (size_t)b * 16);

    f32x4 of[4];
#pragma unroll
    for (int mt = 0; mt < 4; mt++) of[mt] = (f32x4){0.f, 0.f, 0.f, 0.f};
    float ls0 = 0.f, ls1 = 0.f;

    const int r_in = lane >> 3, c8 = lane & 7;
    const int swz = (c8 ^ r_in) << 3;   // chunk-invariant staging swizzle
    const short* kbase = qkv + ((size_t)b * SEQ) * 1536 + 512 + h * 64 + swz;
    const short* vp = vt + ((size_t)((b * NH + h) * HD) + r_in) * SEQ + swz;
    const int fsw = (l15 & 7);

    for (int kt = 0; kt < SEQ; kt += 128) {
#pragma unroll
        for (int rep = 0; rep < 4; rep++) {         // K: permuted rows
            int c = rep * 4 + w;
            int pr = c * 8 + r_in;                  // physical staged row
            int pt = pr & 63;
            int key = (pr & 64) | (pt & 32) | (((pt >> 2) & 3) << 3)
                    | (((pt >> 4) & 1) << 2) | (pt & 3);
            gll16(kbase + (size_t)(kt + key) * 1536, (char*)Ks + c * 1024);
        }
#pragma unroll
        for (int rep = 0; rep < 4; rep++) {         // V: plain, 2 halves x 8
            int v = rep * 4 + w;
            gll16(vp + (size_t)((v & 7) * 8) * SEQ + kt + (v >> 3) * 64,
                  (char*)Vs + v * 1024);
        }
        __syncthreads();

#pragma unroll
        for (int t = 0; t < 2; t++) {
            // S^T sub-tile (64 permuted keys x 16 q)
            f32x4 sa[4];
#pragma unroll
            for (int g = 0; g < 4; g++) sa[g] = (f32x4){0.f, 0.f, 0.f, 0.f};
#pragma unroll
            for (int ks = 0; ks < 2; ks++) {
                const int dblk = ks * 4 + quad;
#pragma unroll
                for (int g = 0; g < 4; g++) {
                    int row = t * 64 + g * 16 + l15;
                    short8 kf = *(const short8*)((const char*)Ks + row * 128 + ((dblk ^ fsw) << 4));
                    sa[g] = __builtin_amdgcn_mfma_f32_16x16x32_bf16(kf, qf[ks], sa[g], 0, 0, 0);
                }
            }
            // masked softmax numerator (max-free); logical bitpos for slot
            // (g,quad,r) is quad*8 + (g>>1)*32 + (g&1)*4 + r
            u64 mw = mrow[(kt >> 6) + t];
            if ((q >> 6) == (kt >> 6) + t) mw |= 1ull << (q & 63);
            u64 mq2 = mw >> (quad * 8);
            unsigned mlo = (unsigned)mq2, mhi = (unsigned)(mq2 >> 32);
            float pv[4][4];
#pragma unroll
            for (int g = 0; g < 4; g++) {
                unsigned mg = ((g & 2) ? mhi : mlo) >> ((g & 1) * 4);
#pragma unroll
                for (int r = 0; r < 4; r++) {
                    float e = fexp2(sa[g][r] * EXP2SC);
                    e = ((mg >> r) & 1u) ? e : 0.f;
                    pv[g][r] = e;
                    if (g & 1) ls1 += e; else ls0 += e;
                }
            }
            // pack C reg-pairs directly into K=32 B-frags (no shuffles)
            short8 pfrag[2];
#pragma unroll
            for (int g32 = 0; g32 < 2; g32++) {
                uint4v pk;
                pk[0] = __builtin_amdgcn_perm(__float_as_uint(pv[2 * g32][1]),
                                              __float_as_uint(pv[2 * g32][0]), 0x07060302u);
                pk[1] = __builtin_amdgcn_perm(__float_as_uint(pv[2 * g32][3]),
                                              __float_as_uint(pv[2 * g32][2]), 0x07060302u);
                pk[2] = __builtin_amdgcn_perm(__float_as_uint(pv[2 * g32 + 1][1]),
                                              __float_as_uint(pv[2 * g32 + 1][0]), 0x07060302u);
                pk[3] = __builtin_amdgcn_perm(__float_as_uint(pv[2 * g32 + 1][3]),
                                              __float_as_uint(pv[2 * g32 + 1][2]), 0x07060302u);
                pfrag[g32] = __builtin_bit_cast(short8, pk);
            }
            // O^T += V^T . P^T  (16x16x32, 8 MFMAs per sub-tile)
#pragma unroll
            for (int g32 = 0; g32 < 2; g32++) {
                const int u = g32 * 4 + quad;
#pragma unroll
                for (int mt = 0; mt < 4; mt++) {
                    int row = mt * 16 + l15;
                    short8 vf = *(const short8*)((const char*)Vs + t * 8192 + row * 128 + ((u ^ fsw) << 4));
                    of[mt] = __builtin_amdgcn_mfma_f32_16x16x32_bf16(vf, pfrag[g32], of[mt], 0, 0, 0);
                }
            }
        }
        __syncthreads();
    }
    float lsum = ls0 + ls1;
    lsum += __shfl_xor(lsum, 16);
    lsum += __shfl_xor(lsum, 32);
    float inv = 1.f / lsum;              // diagonal always allowed -> lsum > 0
#pragma unroll
    for (int mt = 0; mt < 4; mt++) {
        short4v pk;
#pragma unroll
        for (int r = 0; r < 4; r++) pk[r] = f2bf(of[mt][r] * inv);
        *(short4v*)(out + ((size_t)(b * SEQ + q) * HDIM) + h * 64 + mt * 16 + quad * 4) = pk;
    }
}

// ---------------------------------------------------------------------------
// y = LN(x + r)*g + b, rows of 512. One wave per row (lane holds 8 elems).
__global__ __launch_bounds__(256) void ln_bf16(const short* __restrict__ x,
                                               const short* __restrict__ r,
                                               const float* __restrict__ g,
                                               const float* __restrict__ b,
                                               short* __restrict__ y) {
    const int wv = threadIdx.x >> 6, lane = threadIdx.x & 63;
    const size_t row = (size_t)blockIdx.x * 4 + wv;
    const size_t base = row * HDIM + lane * 8;
    short8 xv = *(const short8*)(x + base);
    float v[8];
#pragma unroll
    for (int i = 0; i < 8; i++) v[i] = bf2f(xv[i]);
    if (r) {
        short8 rv = *(const short8*)(r + base);
#pragma unroll
        for (int i = 0; i < 8; i++) v[i] += bf2f(rv[i]);
    }
    float s = 0.f, ss = 0.f;
#pragma unroll
    for (int i = 0; i < 8; i++) { s += v[i]; ss += v[i] * v[i]; }
#pragma unroll
    for (int off = 1; off < 64; off <<= 1) {
        s  += __shfl_xor(s, off);
        ss += __shfl_xor(ss, off);
    }
    const float mean = s * (1.f / HDIM);
    const float var  = ss * (1.f / HDIM) - mean * mean;
    const float inv  = rsqrtf(var + EPS);
    f32x4 g0 = *(const f32x4*)(g + lane * 8), g1 = *(const f32x4*)(g + lane * 8 + 4);
    f32x4 b0 = *(const f32x4*)(b + lane * 8), b1 = *(const f32x4*)(b + lane * 8 + 4);
    short8 o;
#pragma unroll
    for (int i = 0; i < 4; i++) o[i]     = f2bf((v[i]     - mean) * inv * g0[i] + b0[i]);
#pragma unroll
    for (int i = 0; i < 4; i++) o[i + 4] = f2bf((v[i + 4] - mean) * inv * g1[i] + b1[i]);
    *(short8*)(y + base) = o;
}

// ---------------------------------------------------------------------------
__global__ __launch_bounds__(256) void final_bn(const short* __restrict__ X,
                                                const float* __restrict__ g,
                                                const float* __restrict__ bb,
                                                float* __restrict__ out) {
    int h = blockIdx.x * 256 + threadIdx.x;
    if (h >= HDIM) return;
    float vals[BATCH];
    float m = 0.f;
#pragma unroll
    for (int b = 0; b < BATCH; b++) {
        vals[b] = bf2f(X[(size_t)b * SEQ * HDIM + h]);
        m += vals[b];
    }
    m *= (1.f / BATCH);
    float v = 0.f;
#pragma unroll
    for (int b = 0; b < BATCH; b++) { float d = vals[b] - m; v += d * d; }
    v *= (1.f / BATCH);
    float inv = rsqrtf(v + EPS);
#pragma unroll
    for (int b = 0; b < BATCH; b++)
        out[b * HDIM + h] = (vals[b] - m) * inv * g[h] + bb[h];
}

// ---------------------------------------------------------------------------
extern "C" void kernel_launch(void* const* d_in, const int* in_sizes, int n_in,
                              void* d_out, int out_size, void* d_ws, size_t ws_size,
                              hipStream_t stream) {
    const float* nodes      = (const float*)d_in[0];
    const int*   dist       = (const int*)  d_in[1];
    const float* dense_w    = (const float*)d_in[2];
    const float* dense_b    = (const float*)d_in[3];
    const float* dense_ln_g = (const float*)d_in[4];
    const float* dense_ln_b = (const float*)d_in[5];
    const float* qkv_w      = (const float*)d_in[6];
    const float* qkv_b      = (const float*)d_in[7];
    const float* out_w      = (const float*)d_in[8];
    const float* out_b      = (const float*)d_in[9];
    const float* ln1_g      = (const float*)d_in[10];
    const float* ln1_b      = (const float*)d_in[11];
    const float* ffn_w1     = (const float*)d_in[12];
    const float* ffn_b1     = (const float*)d_in[13];
    const float* ffn_w2     = (const float*)d_in[14];
    const float* ffn_b2     = (const float*)d_in[15];
    const float* ln2_g      = (const float*)d_in[16];
    const float* ln2_b      = (const float*)d_in[17];
    const float* bn_g       = (const float*)d_in[18];
    const float* bn_b       = (const float*)d_in[19];
    float* out = (float*)d_out;

    const int M = BATCH * SEQ;                         // 8192
    const size_t MB = 1024 * 1024;
    char* ws = (char*)d_ws;
    short* Wd   = (short*)(ws + 0 * MB);
    short* Wqkv = (short*)(ws + 1 * MB);
    short* Wo   = (short*)(ws + 9 * MB);
    short* W1   = (short*)(ws + 13 * MB);
    short* W2   = (short*)(ws + 18 * MB);
    u64*   mS   = (u64*)(ws + 23 * MB);
    u64*   mL   = (u64*)(ws + 24 * MB);
    u64*   mG   = (u64*)(ws + 25 * MB);
    short* X    = (short*)(ws + 26 * MB);
    short* QKV  = (short*)(ws + 34 * MB);
    short* Vt   = (short*)(ws + 58 * MB);
    short* AT   = (short*)(ws + 66 * MB);
    short* O2   = (short*)(ws + 74 * MB);
    short* XT   = QKV;
    short* F1   = QKV;
    short* F2   = AT;

    prep_all<<<PREP_W + PREP_N + BATCH * SEQ, 256, 0, stream>>>(
        dense_w, Wd, qkv_w, Wqkv, out_w, Wo, ffn_w1, W1, ffn_w2, W2,
        nodes, XT, dist, mS, mL, mG);

    gemm_bf16<64, 128><<<dim3(HDIM / 128, M / 64), 256, 0, stream>>>(
        XT, Wd, dense_b, O2, nullptr, M, HDIM, IDIM, 0);
    ln_bf16<<<M / 4, 256, 0, stream>>>(O2, nullptr, dense_ln_g, dense_ln_b, X);

    for (int l = 0; l < LAYERS; l++) {
        const short* wqkv = Wqkv + (size_t)l * 3 * HDIM * HDIM;
        const float* bqkv = qkv_b + (size_t)l * 3 * HDIM;
        const short* wo   = Wo + (size_t)l * HDIM * HDIM;
        const float* bo   = out_b + (size_t)l * HDIM;
        const short* w1   = W1 + (size_t)l * FF * HDIM;
        const float* b1   = ffn_b1 + (size_t)l * FF;
        const short* w2   = W2 + (size_t)l * HDIM * FF;
        const float* b2   = ffn_b2 + (size_t)l * HDIM;

        gemm_bf16<128, 64><<<dim3(3 * HDIM / 128, M / 128), 256, 0, stream>>>(
            X, wqkv, bqkv, QKV, Vt, M, 3 * HDIM, HDIM, 0);
        attn_mfma<<<1024, 256, 0, stream>>>(QKV, Vt, mS, mL, mG, AT);
        gemm_bf16<64, 128><<<dim3(HDIM / 128, M / 64), 256, 0, stream>>>(
            AT, wo, bo, O2, nullptr, M, HDIM, HDIM, 0);
        ln_bf16<<<M / 4, 256, 0, stream>>>(X, O2, ln1_g + l * HDIM, ln1_b + l * HDIM, X);
        gemm_bf16<128, 64><<<dim3(FF / 128, M / 128), 256, 0, stream>>>(
            X, w1, b1, F1, nullptr, M, FF, HDIM, 1);
        gemm_bf16<64, 128><<<dim3(HDIM / 128, M / 64), 256, 0, stream>>>(
            F1, w2, b2, F2, nullptr, M, HDIM, FF, 0);
        ln_bf16<<<M / 4, 256, 0, stream>>>(X, F2, ln2_g + l * HDIM, ln2_b + l * HDIM, X);
    }
    final_bn<<<(HDIM + 255) / 256, 256, 0, stream>>>(X, bn_g, bn_b, out);
}